// Round 4
// baseline (3363.452 us; speedup 1.0000x reference)
//
#include <hip/hip_runtime.h>

#define B_    32
#define N_    64
#define IN_   2048
#define D_    32
#define K_    16
#define ITILE 16
#define NTILE (IN_/ITILE)          /* 128 i-tiles */
#define NBG   4                    /* batch-groups of BH */
#define BH    8                    /* batches per block */
#define NBLK  (NTILE*NBG)          /* 512 blocks */
#define PCELLS ((size_t)BH*N_*D_)  /* 16384 */
#define CELLS  ((size_t)B_*N_*D_)  /* 65536 */

// softmax_e(v * INV_LOG2) == 2^((v-max) * (1/ln2)^2)
#define SM_SCALE 2.0813689810056077f

// -----------------------------------------------------------------------------
// route_kernel: one pass over W. Block = (i-tile, batch-group of 8).
// Per-thread live state kept < ~58 VGPRs so the compiler's 64-VGPR choice
// (observed R2/R3) cannot spill: acc[2][8]=16, uh[2][8]=16, W chunk 8, x 4.
// XCD swizzle puts the 4 batch-group blocks of a tile on the same XCD/L2.
// -----------------------------------------------------------------------------
template<bool FIRST>
__global__ __launch_bounds__(1024, 4)
void route_kernel(const float* __restrict__ x, const float* __restrict__ W,
                  const float* __restrict__ os, float* __restrict__ part, int P)
{
    __shared__ float x_s[BH][K_];          // 512 B
    __shared__ float logit_s[2][BH][N_];   // 4 KB, double-buffered on ii parity

    const int tid  = threadIdx.x;
    const int w    = tid >> 6;      // wave 0..15
    const int l    = tid & 63;
    const int d    = l & 31;        // output dim this thread owns
    const int hi   = l >> 5;
    const int slot = w * 2 + hi;    // 0..31
    const int nA   = slot;
    const int nB   = slot + 32;

    // same-tile batch groups adjacent within one XCD (bid%8 = XCD)
    const int virt = (blockIdx.x & 7) * (NBLK / 8) + (blockIdx.x >> 3);
    const int tile = virt >> 2;
    const int bg   = virt & 3;
    const int b0   = bg * BH;
    const int i0   = tile * ITILE;

    float s_acc[2][BH];
    #pragma unroll
    for (int p = 0; p < 2; ++p)
        #pragma unroll
        for (int j = 0; j < BH; ++j) s_acc[p][j] = 0.f;

    const float* wpA = W + (((size_t)nA * IN_ + i0) * D_ + d) * K_;
    const float* wpB = W + (((size_t)nB * IN_ + i0) * D_ + d) * K_;
    const float* osA = os + ((size_t)b0 * N_ + nA) * D_ + d;
    const float* osB = os + ((size_t)b0 * N_ + nB) * D_ + d;

    for (int ii = 0; ii < ITILE; ++ii) {
        const int par = ii & 1;
        __syncthreads();                          // x_s safe to overwrite
        if (tid < BH * (K_ / 4)) {                // 32 threads, one float4 each
            const int jb = tid >> 2, k4 = tid & 3;
            ((float4*)x_s[jb])[k4] =
                ((const float4*)(x + (size_t)(b0 + jb) * (IN_ * K_)
                                   + (size_t)(i0 + ii) * K_))[k4];
        }
        __syncthreads();

        if (FIRST) {
            // c uniform (1/64, folded at store): accumulate dots directly
            #pragma unroll
            for (int k4 = 0; k4 < 4; ++k4) {
                const float4 wa = ((const float4*)wpA)[k4];
                const float4 wb = ((const float4*)wpB)[k4];
                #pragma unroll
                for (int j = 0; j < BH; ++j) {
                    const float4 xv = ((const float4*)x_s[j])[k4];
                    s_acc[0][j] += wa.x*xv.x + wa.y*xv.y + wa.z*xv.z + wa.w*xv.w;
                    s_acc[1][j] += wb.x*xv.x + wb.y*xv.y + wb.z*xv.z + wb.w*xv.w;
                }
            }
        } else {
            float uhA[BH], uhB[BH];
            #pragma unroll
            for (int j = 0; j < BH; ++j) { uhA[j] = 0.f; uhB[j] = 0.f; }
            #pragma unroll
            for (int k4 = 0; k4 < 4; ++k4) {      // only 8 W regs live at a time
                const float4 wa = ((const float4*)wpA)[k4];
                const float4 wb = ((const float4*)wpB)[k4];
                #pragma unroll
                for (int j = 0; j < BH; ++j) {
                    const float4 xv = ((const float4*)x_s[j])[k4];
                    uhA[j] += wa.x*xv.x + wa.y*xv.y + wa.z*xv.z + wa.w*xv.w;
                    uhB[j] += wb.x*xv.x + wb.y*xv.y + wb.z*xv.z + wb.w*xv.w;
                }
            }

            // logits[b][n] = sum_d uh * os  (butterfly over the 32 d-lanes)
            #pragma unroll
            for (int j = 0; j < BH; ++j) {
                float tA = uhA[j] * osA[(size_t)j * (N_ * D_)];
                float tB = uhB[j] * osB[(size_t)j * (N_ * D_)];
                #pragma unroll
                for (int m = 1; m < 32; m <<= 1) {
                    tA += __shfl_xor(tA, m, 64);
                    tB += __shfl_xor(tB, m, 64);
                }
                if (d == 0) {                     // lanes 0 and 32
                    logit_s[par][j][nA] = tA;
                    logit_s[par][j][nB] = tB;
                }
            }
            __syncthreads();
            if (w < BH) {                         // wave = batch, 64 lanes = n
                const float v = logit_s[par][w][l];
                float mx = v;
                #pragma unroll
                for (int m = 1; m < 64; m <<= 1) mx = fmaxf(mx, __shfl_xor(mx, m, 64));
                const float e = exp2f((v - mx) * SM_SCALE);
                float sum = e;
                #pragma unroll
                for (int m = 1; m < 64; m <<= 1) sum += __shfl_xor(sum, m, 64);
                logit_s[par][w][l] = e / sum;
            }
            __syncthreads();
            #pragma unroll
            for (int j = 0; j < BH; ++j) {
                s_acc[0][j] += logit_s[par][j][nA] * uhA[j];
                s_acc[1][j] += logit_s[par][j][nB] * uhB[j];
            }
            // no third barrier: parity buffer isn't rewritten for 2 barriers
        }
        wpA += (size_t)D_ * K_;
        wpB += (size_t)D_ * K_;
    }

    const float scale = FIRST ? (1.0f / 64.0f) : 1.0f;
    if (P == NBLK) {
        float* myp = part + (size_t)virt * PCELLS;   // virtual slot order
        #pragma unroll
        for (int j = 0; j < BH; ++j) {
            myp[((size_t)j * N_ + nA) * D_ + d] = s_acc[0][j] * scale;
            myp[((size_t)j * N_ + nB) * D_ + d] = s_acc[1][j] * scale;
        }
    } else {
        float* myp = part + (size_t)(blockIdx.x % P) * CELLS;
        for (int j = 0; j < BH; ++j) {
            const int b = b0 + j;
            atomicAdd(&myp[((size_t)b * N_ + nA) * D_ + d], s_acc[0][j] * scale);
            atomicAdd(&myp[((size_t)b * N_ + nB) * D_ + d], s_acc[1][j] * scale);
        }
    }
}

// -----------------------------------------------------------------------------
// finish_kernel: s = sum of partials; out = squash(s);
// FINAL=false: os += out (next pass's logit operand); FINAL=true: write d_out.
// -----------------------------------------------------------------------------
template<bool FINAL>
__global__ __launch_bounds__(256)
void finish_kernel(const float* __restrict__ part, int P, int compact,
                   float* __restrict__ os, float* __restrict__ out)
{
    const int gid = blockIdx.x * 256 + threadIdx.x;   // 0..65535
    float v = 0.f;
    if (compact) {
        const int b   = gid >> 11;        // 0..31
        const int rem = gid & 2047;       // n*32+d
        const int bg = b >> 3, jb = b & 7;
        const float* p0 = part + (size_t)bg * PCELLS + (size_t)jb * (N_ * D_) + rem;
        for (int t = 0; t < NTILE; ++t) v += p0[(size_t)t * NBG * PCELLS];
    } else {
        for (int p = 0; p < P; ++p) v += part[(size_t)p * CELLS + gid];
    }
    float sq = v * v;
    #pragma unroll
    for (int m = 1; m < 32; m <<= 1) sq += __shfl_xor(sq, m, 64);  // sum over d
    const float scale = sqrtf(sq) / (1.0f + sq);
    const float o = v * scale;
    if (FINAL) out[gid] = o;
    else       os[gid] += o;
}

extern "C" void kernel_launch(void* const* d_in, const int* in_sizes, int n_in,
                              void* d_out, int out_size, void* d_ws, size_t ws_size,
                              hipStream_t stream)
{
    const float* x = (const float*)d_in[0];
    const float* W = (const float*)d_in[1];
    float* out = (float*)d_out;

    int P = NBLK;
    int compact = 1;
    float* part = (float*)d_ws;
    float* os;
    const size_t need = (size_t)NBLK * PCELLS * 4 + CELLS * 4;
    if (ws_size >= need) {
        os = part + (size_t)NBLK * PCELLS;
    } else {
        compact = 0;
        long long avail = (long long)(ws_size / 4) - (long long)CELLS;
        long long p = avail > 0 ? avail / (long long)CELLS : 1;
        P = (int)p; if (P < 1) P = 1; if (P > NBLK) P = NBLK;
        os = part + (size_t)P * CELLS;
    }

    hipMemsetAsync(os, 0, CELLS * 4, stream);

    for (int it = 0; it < 3; ++it) {
        if (!compact) hipMemsetAsync(part, 0, (size_t)P * CELLS * 4, stream);
        if (it == 0) route_kernel<true ><<<NBLK, 1024, 0, stream>>>(x, W, os, part, compact ? NBLK : P);
        else         route_kernel<false><<<NBLK, 1024, 0, stream>>>(x, W, os, part, compact ? NBLK : P);
        if (it < 2)  finish_kernel<false><<<CELLS / 256, 256, 0, stream>>>(part, P, compact, os, nullptr);
        else         finish_kernel<true ><<<CELLS / 256, 256, 0, stream>>>(part, P, compact, nullptr, out);
    }
}

// Round 5
// 635.670 us; speedup vs baseline: 5.2912x; 5.2912x over previous
//
#include <hip/hip_runtime.h>

#define B_    32
#define N_    64
#define IN_   2048
#define D_    32
#define K_    16
#define ITILE 16
#define NTILE (IN_/ITILE)          /* 128 i-tiles */
#define NBG   8                    /* batch groups */
#define BH    4                    /* batches per block */
#define NBLK  (NTILE*NBG)          /* 1024 blocks */
#define PCELLS ((size_t)BH*N_*D_)  /* 8192 */
#define CELLS  ((size_t)B_*N_*D_)  /* 65536 */

// softmax_e(v * INV_LOG2) == 2^((v-max) * (1/ln2)^2)
#define SM_SCALE 2.0813689810056077f

// -----------------------------------------------------------------------------
// route_kernel: one pass over W. Block = 256 threads = (i-tile, batch-group
// of 4). 256-thread blocks + __launch_bounds__(256,1) so the allocator is NOT
// occupancy-pinned to 64 VGPRs (R2-R4: 1024-thread blocks spilled 3+ GB to
// scratch). Live state ~56 regs: s_acc[8][4]=32, uh[4], W float4, addr.
// uh round-trips through LDS across the softmax barrier. x reads are
// wave-uniform -> scalar loads (SGPRs). XCD swizzle: 8 same-tile blocks on
// one XCD so the per-i 128 KB W slice is L2-resident for 7/8 readers.
// -----------------------------------------------------------------------------
template<bool FIRST>
__global__ __launch_bounds__(256, 1)
void route_kernel(const float* __restrict__ x, const float* __restrict__ W,
                  const float* __restrict__ os, float* __restrict__ part, int P)
{
    __shared__ float uh_s[BH][N_][D_];   // 32 KB (unused & elided for FIRST)
    __shared__ float logit_s[BH][N_];    // 1 KB

    const int tid  = threadIdx.x;   // 0..255
    const int w    = tid >> 6;      // wave 0..3
    const int l    = tid & 63;
    const int d    = l & 31;        // output dim this thread owns
    const int hi   = l >> 5;
    const int slot = w * 2 + hi;    // 0..7 -> n = r*8 + slot

    // 8 same-tile batch-group blocks consecutive on one XCD (bid%8 = XCD)
    const int virt = (blockIdx.x & 7) * (NBLK / 8) + (blockIdx.x >> 3);
    const int tile = virt >> 3;
    const int bg   = virt & 7;
    const int b0   = bg * BH;
    const int i0   = tile * ITILE;

    float s_acc[8][BH];             // 32 VGPRs
    #pragma unroll
    for (int r = 0; r < 8; ++r)
        #pragma unroll
        for (int jb = 0; jb < BH; ++jb) s_acc[r][jb] = 0.f;

    for (int ii = 0; ii < ITILE; ++ii) {
        const int i = i0 + ii;
        const float* xb    = x + (size_t)b0 * (IN_ * K_) + (size_t)i * K_;
        const float* wbase = W + (((size_t)slot * IN_ + i) * D_ + d) * K_;

        // ---- phase A: uh for all 8 n-slots; stash to LDS; logit partials
        #pragma unroll
        for (int r = 0; r < 8; ++r) {
            const int n = r * 8 + slot;
            const float4* wp = (const float4*)(wbase + (size_t)r * 8 * IN_ * D_ * K_);
            float uh[BH] = {0.f, 0.f, 0.f, 0.f};
            #pragma unroll
            for (int k4 = 0; k4 < 4; ++k4) {
                const float4 wv = wp[k4];
                #pragma unroll
                for (int jb = 0; jb < BH; ++jb) {
                    // uniform address -> scalar load (no VGPR cost, K$ hit)
                    const float4 xv = *(const float4*)(xb + (size_t)jb * (IN_ * K_) + k4 * 4);
                    uh[jb] += wv.x*xv.x + wv.y*xv.y + wv.z*xv.z + wv.w*xv.w;
                }
            }
            if (FIRST) {
                #pragma unroll
                for (int jb = 0; jb < BH; ++jb) s_acc[r][jb] += uh[jb];
            } else {
                #pragma unroll
                for (int jb = 0; jb < BH; ++jb) uh_s[jb][n][d] = uh[jb];
                #pragma unroll
                for (int jb = 0; jb < BH; ++jb) {
                    float t = uh[jb] * os[((size_t)(b0 + jb) * N_ + n) * D_ + d];
                    #pragma unroll
                    for (int m = 1; m < 32; m <<= 1) t += __shfl_xor(t, m, 64);
                    if (d == 0) logit_s[jb][n] = t;     // lanes 0 & 32
                }
            }
        }

        if (!FIRST) {
            __syncthreads();
            // ---- softmax over n: wave w <-> batch jb=w, 64 lanes = n
            {
                const float v = logit_s[w][l];
                float mx = v;
                #pragma unroll
                for (int m = 1; m < 64; m <<= 1) mx = fmaxf(mx, __shfl_xor(mx, m, 64));
                const float e = exp2f((v - mx) * SM_SCALE);
                float sum = e;
                #pragma unroll
                for (int m = 1; m < 64; m <<= 1) sum += __shfl_xor(sum, m, 64);
                logit_s[w][l] = e / sum;
            }
            __syncthreads();
            // ---- phase C: weighted accumulate from LDS
            #pragma unroll
            for (int r = 0; r < 8; ++r) {
                const int n = r * 8 + slot;
                #pragma unroll
                for (int jb = 0; jb < BH; ++jb)
                    s_acc[r][jb] += logit_s[jb][n] * uh_s[jb][n][d];
            }
            __syncthreads();   // uh_s/logit_s reused next ii
        }
    }

    const float scale = FIRST ? (1.0f / 64.0f) : 1.0f;
    if (P == NBLK) {
        float* myp = part + (size_t)virt * PCELLS;
        #pragma unroll
        for (int r = 0; r < 8; ++r) {
            const int n = r * 8 + slot;
            #pragma unroll
            for (int jb = 0; jb < BH; ++jb)
                myp[((size_t)jb * N_ + n) * D_ + d] = s_acc[r][jb] * scale;
        }
    } else {
        float* myp = part + (size_t)(blockIdx.x % P) * CELLS;
        for (int r = 0; r < 8; ++r) {
            const int n = r * 8 + slot;
            for (int jb = 0; jb < BH; ++jb)
                atomicAdd(&myp[((size_t)(b0 + jb) * N_ + n) * D_ + d], s_acc[r][jb] * scale);
        }
    }
}

// -----------------------------------------------------------------------------
// finish_kernel: s = sum of partials; out = squash(s);
// FINAL=false: os += out (next pass's logit operand); FINAL=true: write d_out.
// -----------------------------------------------------------------------------
template<bool FINAL>
__global__ __launch_bounds__(256)
void finish_kernel(const float* __restrict__ part, int P, int compact,
                   float* __restrict__ os, float* __restrict__ out)
{
    const int gid = blockIdx.x * 256 + threadIdx.x;   // 0..65535
    float v = 0.f;
    if (compact) {
        const int b   = gid >> 11;        // 0..31
        const int rem = gid & 2047;       // n*32+d
        const int bg = b >> 2, jb = b & 3;
        const float* p0 = part + (size_t)bg * PCELLS + (size_t)jb * (N_ * D_) + rem;
        for (int t = 0; t < NTILE; ++t) v += p0[(size_t)t * NBG * PCELLS];
    } else {
        for (int p = 0; p < P; ++p) v += part[(size_t)p * CELLS + gid];
    }
    float sq = v * v;
    #pragma unroll
    for (int m = 1; m < 32; m <<= 1) sq += __shfl_xor(sq, m, 64);  // sum over d
    const float scale = sqrtf(sq) / (1.0f + sq);
    const float o = v * scale;
    if (FINAL) out[gid] = o;
    else       os[gid] += o;
}

extern "C" void kernel_launch(void* const* d_in, const int* in_sizes, int n_in,
                              void* d_out, int out_size, void* d_ws, size_t ws_size,
                              hipStream_t stream)
{
    const float* x = (const float*)d_in[0];
    const float* W = (const float*)d_in[1];
    float* out = (float*)d_out;

    int P = NBLK;
    int compact = 1;
    float* part = (float*)d_ws;
    float* os;
    const size_t need = (size_t)NBLK * PCELLS * 4 + CELLS * 4;
    if (ws_size >= need) {
        os = part + (size_t)NBLK * PCELLS;
    } else {
        compact = 0;
        long long avail = (long long)(ws_size / 4) - (long long)CELLS;
        long long p = avail > 0 ? avail / (long long)CELLS : 1;
        P = (int)p; if (P < 1) P = 1; if (P > NBLK) P = NBLK;
        os = part + (size_t)P * CELLS;
    }

    hipMemsetAsync(os, 0, CELLS * 4, stream);

    for (int it = 0; it < 3; ++it) {
        if (!compact) hipMemsetAsync(part, 0, (size_t)P * CELLS * 4, stream);
        if (it == 0) route_kernel<true ><<<NBLK, 256, 0, stream>>>(x, W, os, part, compact ? NBLK : P);
        else         route_kernel<false><<<NBLK, 256, 0, stream>>>(x, W, os, part, compact ? NBLK : P);
        if (it < 2)  finish_kernel<false><<<CELLS / 256, 256, 0, stream>>>(part, P, compact, os, nullptr);
        else         finish_kernel<true ><<<CELLS / 256, 256, 0, stream>>>(part, P, compact, nullptr, out);
    }
}